// Round 1
// baseline (425.348 us; speedup 1.0000x reference)
//
#include <hip/hip_runtime.h>

#define SEQ 2048
#define NTOK 4096
#define DM 1024

typedef __attribute__((ext_vector_type(4))) float f32x4;
typedef __attribute__((ext_vector_type(8))) short short8;
typedef __attribute__((ext_vector_type(4))) short short4v;

__device__ __forceinline__ short f2bf(float f) {
  union { float f; unsigned u; } x; x.f = f;
  unsigned r = x.u + 0x7fffu + ((x.u >> 16) & 1u);
  return (short)(r >> 16);
}

__device__ __forceinline__ void async_load16(const void* g, void* l) {
  __builtin_amdgcn_global_load_lds(
      (const __attribute__((address_space(1))) void*)g,
      (__attribute__((address_space(3))) void*)l, 16, 0, 0);
}

// f32 [K][N] -> bf16 [N][K]
__global__ void __launch_bounds__(256) transpose_cast_w(
    const float* __restrict__ in, short* __restrict__ out, int K, int N) {
  __shared__ float t[32][33];
  const int tx = threadIdx.x, ty = threadIdx.y;
  const int n = blockIdx.x * 32 + tx;
#pragma unroll
  for (int i = 0; i < 4; ++i) {
    int k = blockIdx.y * 32 + ty + i * 8;
    t[ty + i * 8][tx] = in[(size_t)k * N + n];
  }
  __syncthreads();
  const int k2 = blockIdx.y * 32 + tx;
#pragma unroll
  for (int i = 0; i < 4; ++i) {
    int n2 = blockIdx.x * 32 + ty + i * 8;
    out[(size_t)n2 * K + k2] = f2bf(t[tx][ty + i * 8]);
  }
}

__global__ void __launch_bounds__(256) cast_bf16(
    const float* __restrict__ in, short* __restrict__ out) {
  int i = blockIdx.x * 256 + threadIdx.x;
  f32x4 v = ((const f32x4*)in)[i];
  short4v o;
#pragma unroll
  for (int j = 0; j < 4; ++j) o[j] = f2bf(v[j]);
  ((short4v*)out)[i] = o;
}

// C[M,N] = A[M,K](bf16) @ Bt[N,K](bf16)^T + bias. EPI: 0=bf16 out, 1=bf16 gelu, 2=f32 out
template <int EPI>
__global__ void __launch_bounds__(256, 2) gemm_bt(
    const short* __restrict__ A, const short* __restrict__ Bt,
    const float* __restrict__ bias, void* __restrict__ Cout,
    int M, int N, int K) {
  __shared__ __align__(16) short As[128 * 64];
  __shared__ __align__(16) short Bs[128 * 64];
  const int w = threadIdx.x >> 6, lane = threadIdx.x & 63;
  const int hi = lane >> 4, lo = lane & 15;
  const int bm = blockIdx.y, bn = blockIdx.x;
  const int wr = w >> 1, wc = w & 1;
  f32x4 acc[4][4] = {};
  const int nkt = K >> 6;
  for (int kt = 0; kt < nkt; ++kt) {
#pragma unroll
    for (int j = 0; j < 4; ++j) {
      int c = (j * 4 + w) * 64 + lane;  // 16B-chunk index 0..1023
      int r = c >> 3;
      int scc = (c & 7) ^ (r & 7);      // inverse-swizzled global source chunk
      async_load16(A + (size_t)(bm * 128 + r) * K + kt * 64 + scc * 8,
                   As + (j * 4 + w) * 512);
      async_load16(Bt + (size_t)(bn * 128 + r) * K + kt * 64 + scc * 8,
                   Bs + (j * 4 + w) * 512);
    }
    __syncthreads();
#pragma unroll
    for (int ks = 0; ks < 2; ++ks) {
      short8 af[4], bf[4];
#pragma unroll
      for (int m = 0; m < 4; ++m) {
        int row = wr * 64 + m * 16 + lo;
        int ch = (ks * 4 + hi) ^ (row & 7);
        af[m] = *(const short8*)(As + row * 64 + ch * 8);
      }
#pragma unroll
      for (int n = 0; n < 4; ++n) {
        int row = wc * 64 + n * 16 + lo;
        int ch = (ks * 4 + hi) ^ (row & 7);
        bf[n] = *(const short8*)(Bs + row * 64 + ch * 8);
      }
#pragma unroll
      for (int m = 0; m < 4; ++m)
#pragma unroll
        for (int n = 0; n < 4; ++n)
          acc[m][n] = __builtin_amdgcn_mfma_f32_16x16x32_bf16(af[m], bf[n], acc[m][n], 0, 0, 0);
    }
    __syncthreads();
  }
  const int colb = bn * 128 + wc * 64 + lo;
#pragma unroll
  for (int m = 0; m < 4; ++m) {
    int row0 = bm * 128 + wr * 64 + m * 16 + hi * 4;
#pragma unroll
    for (int n = 0; n < 4; ++n) {
      int col = colb + n * 16;
      float bs = bias[col];
#pragma unroll
      for (int j = 0; j < 4; ++j) {
        float v = acc[m][n][j] + bs;
        if (EPI == 1) v = 0.5f * v * (1.f + erff(v * 0.70710678f));
        size_t idx = (size_t)(row0 + j) * N + col;
        if (EPI == 2) ((float*)Cout)[idx] = v;
        else ((short*)Cout)[idx] = f2bf(v);
      }
    }
  }
}

// Vb [B][S][DM] -> Vt [B*H][64][S]
__global__ void __launch_bounds__(256) transpose_v(
    const short* __restrict__ Vb, short* __restrict__ Vt) {
  __shared__ short t[64][65];
  const int bh = blockIdx.y, s0 = blockIdx.x * 64;
  const int b = bh >> 4, h = bh & 15;
  const int tid = threadIdx.x;
#pragma unroll
  for (int i = 0; i < 16; ++i) {
    int e = i * 256 + tid;
    int r = e >> 6, c = e & 63;
    t[c][r] = Vb[(size_t)(b * SEQ + s0 + r) * DM + h * 64 + c];
  }
  __syncthreads();
#pragma unroll
  for (int i = 0; i < 16; ++i) {
    int e = i * 256 + tid;
    int d = e >> 6, sc = e & 63;
    Vt[(size_t)bh * 64 * SEQ + (size_t)d * SEQ + s0 + sc] = t[d][sc];
  }
}

// grid (S/64, B*H); 4 waves, 16 q-rows each. Swapped QK^T flash.
__global__ void __launch_bounds__(256, 2) attn_kernel(
    const short* __restrict__ Qb, const short* __restrict__ Kb,
    const short* __restrict__ Vt, short* __restrict__ ctx) {
  const int w = threadIdx.x >> 6, lane = threadIdx.x & 63;
  const int hi = lane >> 4, lo = lane & 15;
  const int qt = blockIdx.x, bh = blockIdx.y;
  const int b = bh >> 4, h = bh & 15;
  const int qrow = qt * 64 + w * 16;
  __shared__ __align__(16) short P[4][16][72];
  const short* qp = Qb + (size_t)(b * SEQ + qrow + lo) * DM + h * 64;
  short8 bq0 = *(const short8*)(qp + hi * 8);
  short8 bq1 = *(const short8*)(qp + 32 + hi * 8);
  const short* kb = Kb + (size_t)(b * SEQ) * DM + h * 64;
  const short* vb = Vt + (size_t)bh * 64 * SEQ;
  float m = -1e30f, l = 0.f;
  f32x4 o[4] = {};
  for (int kt = 0; kt < SEQ / 64; ++kt) {
    f32x4 s[4] = {};
#pragma unroll
    for (int g = 0; g < 4; ++g) {
      const short* kr = kb + (size_t)(kt * 64 + g * 16 + lo) * DM;
      short8 ka0 = *(const short8*)(kr + hi * 8);
      short8 ka1 = *(const short8*)(kr + 32 + hi * 8);
      s[g] = __builtin_amdgcn_mfma_f32_16x16x32_bf16(ka0, bq0, s[g], 0, 0, 0);
      s[g] = __builtin_amdgcn_mfma_f32_16x16x32_bf16(ka1, bq1, s[g], 0, 0, 0);
    }
    float sv[16];
    float mt = -1e30f;
#pragma unroll
    for (int g = 0; g < 4; ++g)
#pragma unroll
      for (int j = 0; j < 4; ++j) {
        float v = s[g][j] * 0.125f;
        sv[g * 4 + j] = v;
        mt = fmaxf(mt, v);
      }
    mt = fmaxf(mt, __shfl_xor(mt, 16));
    mt = fmaxf(mt, __shfl_xor(mt, 32));
    float mnew = fmaxf(m, mt);
    float alpha = __expf(m - mnew);
    float rs = 0.f;
    float pv[16];
#pragma unroll
    for (int i = 0; i < 16; ++i) {
      float p = __expf(sv[i] - mnew);
      pv[i] = p;
      rs += p;
    }
    rs += __shfl_xor(rs, 16);
    rs += __shfl_xor(rs, 32);
    l = l * alpha + rs;
    m = mnew;
#pragma unroll
    for (int j = 0; j < 4; ++j) {
      float aj = __shfl(alpha, hi * 4 + j);
#pragma unroll
      for (int a = 0; a < 4; ++a) o[a][j] *= aj;
    }
    __syncthreads();  // prior iter's P reads complete
#pragma unroll
    for (int a = 0; a < 4; ++a) {
      short4v t;
#pragma unroll
      for (int j = 0; j < 4; ++j) t[j] = f2bf(pv[a * 4 + j]);
      *(short4v*)&P[w][lo][a * 16 + hi * 4] = t;
    }
    __syncthreads();  // P writes visible
#pragma unroll
    for (int ks = 0; ks < 2; ++ks) {
      short8 pa = *(const short8*)&P[w][lo][ks * 32 + hi * 8];
#pragma unroll
      for (int a = 0; a < 4; ++a) {
        short8 vv = *(const short8*)(vb + (size_t)(a * 16 + lo) * SEQ + kt * 64 + ks * 32 + hi * 8);
        o[a] = __builtin_amdgcn_mfma_f32_16x16x32_bf16(pa, vv, o[a], 0, 0, 0);
      }
    }
  }
#pragma unroll
  for (int j = 0; j < 4; ++j) {
    float lj = __shfl(l, hi * 4 + j);
    float inv = 1.f / lj;
    int srow = qrow + hi * 4 + j;
#pragma unroll
    for (int a = 0; a < 4; ++a)
      ctx[(size_t)(b * SEQ + srow) * DM + h * 64 + a * 16 + lo] = f2bf(o[a][j] * inv);
  }
}

// out = LN(x + y)*g + beta ; optional bf16 copy
__global__ void __launch_bounds__(256) residual_ln(
    const float* __restrict__ xr, const float* __restrict__ yr,
    const float* __restrict__ g, const float* __restrict__ beta,
    float* __restrict__ outf, short* __restrict__ outb) {
  const int row = blockIdx.x;
  const int t = threadIdx.x;
  const size_t base = (size_t)row * DM;
  f32x4 xv = ((const f32x4*)(xr + base))[t];
  f32x4 yv = ((const f32x4*)(yr + base))[t];
  f32x4 v = xv + yv;
  float s = v[0] + v[1] + v[2] + v[3];
  float s2 = v[0] * v[0] + v[1] * v[1] + v[2] * v[2] + v[3] * v[3];
#pragma unroll
  for (int off = 1; off < 64; off <<= 1) {
    s += __shfl_xor(s, off);
    s2 += __shfl_xor(s2, off);
  }
  __shared__ float rs[4], rs2[4];
  if ((t & 63) == 0) { rs[t >> 6] = s; rs2[t >> 6] = s2; }
  __syncthreads();
  s = rs[0] + rs[1] + rs[2] + rs[3];
  s2 = rs2[0] + rs2[1] + rs2[2] + rs2[3];
  float mu = s * (1.f / DM);
  float var = s2 * (1.f / DM) - mu * mu;
  float rstd = rsqrtf(var + 1e-5f);
  f32x4 gv = ((const f32x4*)g)[t];
  f32x4 bv = ((const f32x4*)beta)[t];
  f32x4 ov;
#pragma unroll
  for (int j = 0; j < 4; ++j) ov[j] = (v[j] - mu) * rstd * gv[j] + bv[j];
  ((f32x4*)(outf + base))[t] = ov;
  if (outb) {
    short4v sb;
#pragma unroll
    for (int j = 0; j < 4; ++j) sb[j] = f2bf(ov[j]);
    ((short4v*)(outb + base))[t] = sb;
  }
}

extern "C" void kernel_launch(void* const* d_in, const int* in_sizes, int n_in,
                              void* d_out, int out_size, void* d_ws, size_t ws_size,
                              hipStream_t stream) {
  (void)in_sizes; (void)n_in; (void)out_size; (void)ws_size;
  const float* x   = (const float*)d_in[0];
  const float* Wq  = (const float*)d_in[1];
  const float* bq  = (const float*)d_in[2];
  const float* Wk  = (const float*)d_in[3];
  const float* bk  = (const float*)d_in[4];
  const float* Wv  = (const float*)d_in[5];
  const float* bv  = (const float*)d_in[6];
  const float* Wo  = (const float*)d_in[7];
  const float* bo  = (const float*)d_in[8];
  const float* g1  = (const float*)d_in[9];
  const float* b1  = (const float*)d_in[10];
  const float* Wf1 = (const float*)d_in[11];
  const float* bf1 = (const float*)d_in[12];
  const float* Wf2 = (const float*)d_in[13];
  const float* bf2 = (const float*)d_in[14];
  const float* g2  = (const float*)d_in[15];
  const float* b2  = (const float*)d_in[16];

  char* ws = (char*)d_ws;
  const size_t MB = 1u << 20;
  short* Wtq  = (short*)(ws + 0 * MB);
  short* Wtk  = (short*)(ws + 2 * MB);
  short* Wtv  = (short*)(ws + 4 * MB);
  short* Wto  = (short*)(ws + 6 * MB);
  short* Wtf1 = (short*)(ws + 8 * MB);
  short* Wtf2 = (short*)(ws + 12 * MB);
  short* xb   = (short*)(ws + 16 * MB);
  short* Qb   = (short*)(ws + 24 * MB);
  short* Kb   = (short*)(ws + 32 * MB);
  short* Vb   = (short*)(ws + 40 * MB);
  short* Vt   = (short*)(ws + 48 * MB);
  short* ctxb = (short*)(ws + 56 * MB);
  float* aout = (float*)(ws + 64 * MB);
  float* x1f  = (float*)(ws + 80 * MB);
  short* x1b  = xb;          // xb dead after QKV gemms
  short* hb   = Qb;          // spans Qb+Kb, dead after attention
  float* ffo  = (float*)(ws + 40 * MB);  // spans Vb+Vt, dead after attention

  dim3 b32(32, 8, 1);
  transpose_cast_w<<<dim3(32, 32), b32, 0, stream>>>(Wq, Wtq, 1024, 1024);
  transpose_cast_w<<<dim3(32, 32), b32, 0, stream>>>(Wk, Wtk, 1024, 1024);
  transpose_cast_w<<<dim3(32, 32), b32, 0, stream>>>(Wv, Wtv, 1024, 1024);
  transpose_cast_w<<<dim3(32, 32), b32, 0, stream>>>(Wo, Wto, 1024, 1024);
  transpose_cast_w<<<dim3(64, 32), b32, 0, stream>>>(Wf1, Wtf1, 1024, 2048);
  transpose_cast_w<<<dim3(32, 64), b32, 0, stream>>>(Wf2, Wtf2, 2048, 1024);
  cast_bf16<<<4096, 256, 0, stream>>>(x, xb);

  gemm_bt<0><<<dim3(8, 32), 256, 0, stream>>>(xb, Wtq, bq, Qb, NTOK, 1024, 1024);
  gemm_bt<0><<<dim3(8, 32), 256, 0, stream>>>(xb, Wtk, bk, Kb, NTOK, 1024, 1024);
  gemm_bt<0><<<dim3(8, 32), 256, 0, stream>>>(xb, Wtv, bv, Vb, NTOK, 1024, 1024);

  transpose_v<<<dim3(32, 32), 256, 0, stream>>>(Vb, Vt);
  attn_kernel<<<dim3(32, 32), 256, 0, stream>>>(Qb, Kb, Vt, ctxb);

  gemm_bt<2><<<dim3(8, 32), 256, 0, stream>>>(ctxb, Wto, bo, aout, NTOK, 1024, 1024);
  residual_ln<<<4096, 256, 0, stream>>>(x, aout, g1, b1, x1f, x1b);
  gemm_bt<1><<<dim3(16, 32), 256, 0, stream>>>(x1b, Wtf1, bf1, hb, NTOK, 2048, 1024);
  gemm_bt<2><<<dim3(8, 32), 256, 0, stream>>>(hb, Wtf2, bf2, ffo, NTOK, 1024, 2048);
  residual_ln<<<4096, 256, 0, stream>>>(x1f, ffo, g2, b2, (float*)d_out, nullptr);
}

// Round 3
// 296.455 us; speedup vs baseline: 1.4348x; 1.4348x over previous
//
#include <hip/hip_runtime.h>

#define SEQ 2048
#define NTOK 4096
#define DM 1024
#define LDQK 3072

typedef __attribute__((ext_vector_type(4))) float f32x4;
typedef __attribute__((ext_vector_type(8))) short short8;
typedef __attribute__((ext_vector_type(4))) short short4v;

__device__ __forceinline__ short f2bf(float f) {
  union { float f; unsigned u; } x; x.f = f;
  unsigned r = x.u + 0x7fffu + ((x.u >> 16) & 1u);
  return (short)(r >> 16);
}

__device__ __forceinline__ void async_load16(const void* g, void* l) {
  __builtin_amdgcn_global_load_lds(
      (const __attribute__((address_space(1))) void*)g,
      (__attribute__((address_space(3))) void*)l, 16, 0, 0);
}

// f32 [K][N] -> bf16 [N][K]
__global__ void __launch_bounds__(256) transpose_cast_w(
    const float* __restrict__ in, short* __restrict__ out, int K, int N) {
  __shared__ float t[32][33];
  const int tx = threadIdx.x, ty = threadIdx.y;
  const int n = blockIdx.x * 32 + tx;
#pragma unroll
  for (int i = 0; i < 4; ++i) {
    int k = blockIdx.y * 32 + ty + i * 8;
    t[ty + i * 8][tx] = in[(size_t)k * N + n];
  }
  __syncthreads();
  const int k2 = blockIdx.y * 32 + tx;
#pragma unroll
  for (int i = 0; i < 4; ++i) {
    int n2 = blockIdx.x * 32 + ty + i * 8;
    out[(size_t)n2 * K + k2] = f2bf(t[tx][ty + i * 8]);
  }
}

__global__ void __launch_bounds__(256) cast_bf16(
    const float* __restrict__ in, short* __restrict__ out) {
  int i = blockIdx.x * 256 + threadIdx.x;
  f32x4 v = ((const f32x4*)in)[i];
  short4v o;
#pragma unroll
  for (int j = 0; j < 4; ++j) o[j] = f2bf(v[j]);
  ((short4v*)out)[i] = o;
}

// C[M,N] = A[M,K](bf16) @ Bt[N,K](bf16)^T + bias.
// EPI: 0=bf16 out, 1=bf16 gelu, 2=f32 out. TRIPLE: bias region per 8 n-tiles.
template <int EPI, bool TRIPLE>
__global__ void __launch_bounds__(256, 2) gemm_bt(
    const short* __restrict__ A, const short* __restrict__ Bt,
    const float* __restrict__ b0, const float* __restrict__ b1,
    const float* __restrict__ b2, void* __restrict__ Cout,
    int M, int N, int K) {
  __shared__ __align__(16) short As[128 * 64];
  __shared__ __align__(16) short Bs[128 * 64];
  const int w = threadIdx.x >> 6, lane = threadIdx.x & 63;
  const int hi = lane >> 4, lo = lane & 15;
  const int bm = blockIdx.y, bn = blockIdx.x;
  const int wr = w >> 1, wc = w & 1;
  f32x4 acc[4][4] = {};
  const int nkt = K >> 6;
  for (int kt = 0; kt < nkt; ++kt) {
#pragma unroll
    for (int j = 0; j < 4; ++j) {
      int c = (j * 4 + w) * 64 + lane;  // 16B-chunk index 0..1023
      int r = c >> 3;
      int scc = (c & 7) ^ (r & 7);      // inverse-swizzled global source chunk
      async_load16(A + (size_t)(bm * 128 + r) * K + kt * 64 + scc * 8,
                   As + (j * 4 + w) * 512);
      async_load16(Bt + (size_t)(bn * 128 + r) * K + kt * 64 + scc * 8,
                   Bs + (j * 4 + w) * 512);
    }
    __syncthreads();
#pragma unroll
    for (int ks = 0; ks < 2; ++ks) {
      short8 af[4], bf[4];
#pragma unroll
      for (int m = 0; m < 4; ++m) {
        int row = wr * 64 + m * 16 + lo;
        int ch = (ks * 4 + hi) ^ (row & 7);
        af[m] = *(const short8*)(As + row * 64 + ch * 8);
      }
#pragma unroll
      for (int n = 0; n < 4; ++n) {
        int row = wc * 64 + n * 16 + lo;
        int ch = (ks * 4 + hi) ^ (row & 7);
        bf[n] = *(const short8*)(Bs + row * 64 + ch * 8);
      }
#pragma unroll
      for (int m = 0; m < 4; ++m)
#pragma unroll
        for (int n = 0; n < 4; ++n)
          acc[m][n] = __builtin_amdgcn_mfma_f32_16x16x32_bf16(af[m], bf[n], acc[m][n], 0, 0, 0);
    }
    __syncthreads();
  }
  const float* bp = b0;
  if (TRIPLE) { int r = bn >> 3; bp = (r == 0) ? b0 : ((r == 1) ? b1 : b2); }
  const int colb = bn * 128 + wc * 64 + lo;
#pragma unroll
  for (int m = 0; m < 4; ++m) {
    int row0 = bm * 128 + wr * 64 + m * 16 + hi * 4;
#pragma unroll
    for (int n = 0; n < 4; ++n) {
      int col = colb + n * 16;
      float bs = bp[TRIPLE ? (col & 1023) : col];
#pragma unroll
      for (int j = 0; j < 4; ++j) {
        float v = acc[m][n][j] + bs;
        if (EPI == 1) v = 0.5f * v * (1.f + erff(v * 0.70710678f));
        size_t idx = (size_t)(row0 + j) * N + col;
        if (EPI == 2) ((float*)Cout)[idx] = v;
        else ((short*)Cout)[idx] = f2bf(v);
      }
    }
  }
}

// V section of QKV [tok][LDQK] -> Vt [B*H][64][SEQ]
__global__ void __launch_bounds__(256) transpose_v(
    const short* __restrict__ Vb, short* __restrict__ Vt) {
  __shared__ short t[64][65];
  const int bh = blockIdx.y, s0 = blockIdx.x * 64;
  const int b = bh >> 4, h = bh & 15;
  const int tid = threadIdx.x;
#pragma unroll
  for (int i = 0; i < 16; ++i) {
    int e = i * 256 + tid;
    int r = e >> 6, c = e & 63;
    t[c][r] = Vb[(size_t)(b * SEQ + s0 + r) * LDQK + h * 64 + c];
  }
  __syncthreads();
#pragma unroll
  for (int i = 0; i < 16; ++i) {
    int e = i * 256 + tid;
    int d = e >> 6, sc = e & 63;
    Vt[(size_t)bh * 64 * SEQ + (size_t)d * SEQ + s0 + sc] = t[d][sc];
  }
}

// Flash attention. grid (SEQ/128, B*H), 256 thr, 4 waves x 32 q-rows.
// Swapped QK^T (P lane-local per q-row=lo), P staged via wave-private
// XOR-swizzled LDS (no barriers), PV with 16x16x32 mfma. R1-proven math.
__global__ void __launch_bounds__(256, 2) attn_kernel(
    const short* __restrict__ Qb, const short* __restrict__ Kb,
    const short* __restrict__ Vt, short* __restrict__ ctx) {
  const int w = threadIdx.x >> 6, lane = threadIdx.x & 63;
  const int hi = lane >> 4, lo = lane & 15;
  const int bh = blockIdx.y, b = bh >> 4, h = bh & 15;
  const int qbase = blockIdx.x * 128 + w * 32;
  const float C = 0.18033688f;  // 0.125 * log2(e)

  __shared__ __align__(16) short P[4][2][16][64];  // [wave][u][qrow][k] 16KB

  const short* qp = Qb + (size_t)(b * SEQ + qbase + lo) * LDQK + h * 64;
  short8 bq[2][2];
#pragma unroll
  for (int u = 0; u < 2; ++u)
#pragma unroll
    for (int c = 0; c < 2; ++c)
      bq[u][c] = *(const short8*)(qp + (size_t)u * 16 * LDQK + c * 32 + hi * 8);

  const short* kb = Kb + (size_t)(b * SEQ) * LDQK + h * 64;
  const short* vb = Vt + (size_t)bh * 64 * SEQ;

  f32x4 o[2][4] = {};
  float m[2] = {-1e30f, -1e30f}, l[2] = {0.f, 0.f};

  for (int kt = 0; kt < SEQ / 64; ++kt) {
    f32x4 s[2][4] = {};
    const short* kbase = kb + (size_t)(kt * 64 + lo) * LDQK;
#pragma unroll
    for (int g = 0; g < 4; ++g) {
      short8 ka0 = *(const short8*)(kbase + (size_t)g * 16 * LDQK + hi * 8);
      short8 ka1 = *(const short8*)(kbase + (size_t)g * 16 * LDQK + 32 + hi * 8);
      s[0][g] = __builtin_amdgcn_mfma_f32_16x16x32_bf16(ka0, bq[0][0], s[0][g], 0, 0, 0);
      s[1][g] = __builtin_amdgcn_mfma_f32_16x16x32_bf16(ka0, bq[1][0], s[1][g], 0, 0, 0);
      s[0][g] = __builtin_amdgcn_mfma_f32_16x16x32_bf16(ka1, bq[0][1], s[0][g], 0, 0, 0);
      s[1][g] = __builtin_amdgcn_mfma_f32_16x16x32_bf16(ka1, bq[1][1], s[1][g], 0, 0, 0);
    }
    short8 vv[2][4];
#pragma unroll
    for (int ks = 0; ks < 2; ++ks)
#pragma unroll
      for (int a = 0; a < 4; ++a)
        vv[ks][a] = *(const short8*)(vb + (size_t)(a * 16 + lo) * SEQ + kt * 64 + ks * 32 + hi * 8);
#pragma unroll
    for (int u = 0; u < 2; ++u) {
      float sv[16];
      float mt = -1e30f;
#pragma unroll
      for (int g = 0; g < 4; ++g)
#pragma unroll
        for (int j = 0; j < 4; ++j) {
          float v = s[u][g][j];
          sv[g * 4 + j] = v;
          mt = fmaxf(mt, v);
        }
      mt = fmaxf(mt, __shfl_xor(mt, 16));
      mt = fmaxf(mt, __shfl_xor(mt, 32));
      float mnew = fmaxf(m[u], mt);
      float alpha = exp2f((m[u] - mnew) * C);
      l[u] *= alpha;
      m[u] = mnew;
#pragma unroll
      for (int j = 0; j < 4; ++j) {
        float aj = __shfl(alpha, hi * 4 + j);
#pragma unroll
        for (int a = 0; a < 4; ++a) o[u][a][j] *= aj;
      }
      float rs = 0.f;
      float mC = mnew * C;
      short* pbase = &P[w][u][0][0];
#pragma unroll
      for (int a = 0; a < 4; ++a) {
        short4v t;
#pragma unroll
        for (int j = 0; j < 4; ++j) {
          float p = exp2f(sv[a * 4 + j] * C - mC);
          rs += p;
          t[j] = f2bf(p);
        }
        // logical chunk 2a+(hi>>1), physical = ^(row&7); row = lo
        int pc = (2 * a + (hi >> 1)) ^ (lo & 7);
        *(short4v*)(pbase + lo * 64 + pc * 8 + (hi & 1) * 4) = t;
      }
      rs += __shfl_xor(rs, 16);
      rs += __shfl_xor(rs, 32);
      l[u] += rs;
#pragma unroll
      for (int ks = 0; ks < 2; ++ks) {
        int pc = (ks * 4 + hi) ^ (lo & 7);
        short8 pa = *(const short8*)(pbase + lo * 64 + pc * 8);
#pragma unroll
        for (int a = 0; a < 4; ++a)
          o[u][a] = __builtin_amdgcn_mfma_f32_16x16x32_bf16(pa, vv[ks][a], o[u][a], 0, 0, 0);
      }
    }
  }
#pragma unroll
  for (int u = 0; u < 2; ++u)
#pragma unroll
    for (int j = 0; j < 4; ++j) {
      float lj = __shfl(l[u], hi * 4 + j);
      float inv = 1.f / lj;
      int row = qbase + u * 16 + hi * 4 + j;
#pragma unroll
      for (int a = 0; a < 4; ++a)
        ctx[(size_t)(b * SEQ + row) * DM + h * 64 + a * 16 + lo] = f2bf(o[u][a][j] * inv);
    }
}

// out = LN(x + y)*g + beta ; optional bf16 copy
__global__ void __launch_bounds__(256) residual_ln(
    const float* __restrict__ xr, const float* __restrict__ yr,
    const float* __restrict__ g, const float* __restrict__ beta,
    float* __restrict__ outf, short* __restrict__ outb) {
  const int row = blockIdx.x;
  const int t = threadIdx.x;
  const size_t base = (size_t)row * DM;
  f32x4 xv = ((const f32x4*)(xr + base))[t];
  f32x4 yv = ((const f32x4*)(yr + base))[t];
  f32x4 v = xv + yv;
  float s = v[0] + v[1] + v[2] + v[3];
  float s2 = v[0] * v[0] + v[1] * v[1] + v[2] * v[2] + v[3] * v[3];
#pragma unroll
  for (int off = 1; off < 64; off <<= 1) {
    s += __shfl_xor(s, off);
    s2 += __shfl_xor(s2, off);
  }
  __shared__ float rs[4], rs2[4];
  if ((t & 63) == 0) { rs[t >> 6] = s; rs2[t >> 6] = s2; }
  __syncthreads();
  s = rs[0] + rs[1] + rs[2] + rs[3];
  s2 = rs2[0] + rs2[1] + rs2[2] + rs2[3];
  float mu = s * (1.f / DM);
  float var = s2 * (1.f / DM) - mu * mu;
  float rstd = rsqrtf(var + 1e-5f);
  f32x4 gv = ((const f32x4*)g)[t];
  f32x4 bv = ((const f32x4*)beta)[t];
  f32x4 ov;
#pragma unroll
  for (int j = 0; j < 4; ++j) ov[j] = (v[j] - mu) * rstd * gv[j] + bv[j];
  ((f32x4*)(outf + base))[t] = ov;
  if (outb) {
    short4v sb;
#pragma unroll
    for (int j = 0; j < 4; ++j) sb[j] = f2bf(ov[j]);
    ((short4v*)(outb + base))[t] = sb;
  }
}

extern "C" void kernel_launch(void* const* d_in, const int* in_sizes, int n_in,
                              void* d_out, int out_size, void* d_ws, size_t ws_size,
                              hipStream_t stream) {
  (void)in_sizes; (void)n_in; (void)out_size; (void)ws_size;
  const float* x   = (const float*)d_in[0];
  const float* Wq  = (const float*)d_in[1];
  const float* bq  = (const float*)d_in[2];
  const float* Wk  = (const float*)d_in[3];
  const float* bk  = (const float*)d_in[4];
  const float* Wv  = (const float*)d_in[5];
  const float* bv  = (const float*)d_in[6];
  const float* Wo  = (const float*)d_in[7];
  const float* bo  = (const float*)d_in[8];
  const float* g1  = (const float*)d_in[9];
  const float* b1  = (const float*)d_in[10];
  const float* Wf1 = (const float*)d_in[11];
  const float* bf1 = (const float*)d_in[12];
  const float* Wf2 = (const float*)d_in[13];
  const float* bf2 = (const float*)d_in[14];
  const float* g2  = (const float*)d_in[15];
  const float* b2  = (const float*)d_in[16];

  char* ws = (char*)d_ws;
  const size_t MB = 1u << 20;
  short* Wqkv = (short*)(ws + 0 * MB);    // [3072][1024] bf16, 6 MB
  short* Wto  = (short*)(ws + 6 * MB);    // 2 MB
  short* Wtf1 = (short*)(ws + 8 * MB);    // 4 MB
  short* Wtf2 = (short*)(ws + 12 * MB);   // 4 MB
  short* xb   = (short*)(ws + 16 * MB);   // 8 MB
  short* QKV  = (short*)(ws + 24 * MB);   // [4096][3072] bf16, 24 MB
  short* Vt   = (short*)(ws + 48 * MB);   // 8 MB
  short* ctxb = (short*)(ws + 56 * MB);   // 8 MB
  float* aout = (float*)(ws + 64 * MB);   // 16 MB
  float* x1f  = (float*)(ws + 80 * MB);   // 16 MB
  short* x1b  = xb;                        // xb dead after QKV gemm
  short* hb   = QKV;                       // QKV dead after attention
  float* ffo  = (float*)(ws + 48 * MB);   // Vt+ctxb dead after O-proj

  dim3 b32(32, 8, 1);
  transpose_cast_w<<<dim3(32, 32), b32, 0, stream>>>(Wq, Wqkv, 1024, 1024);
  transpose_cast_w<<<dim3(32, 32), b32, 0, stream>>>(Wk, Wqkv + 1024 * 1024, 1024, 1024);
  transpose_cast_w<<<dim3(32, 32), b32, 0, stream>>>(Wv, Wqkv + 2048 * 1024, 1024, 1024);
  transpose_cast_w<<<dim3(32, 32), b32, 0, stream>>>(Wo, Wto, 1024, 1024);
  transpose_cast_w<<<dim3(64, 32), b32, 0, stream>>>(Wf1, Wtf1, 1024, 2048);
  transpose_cast_w<<<dim3(32, 64), b32, 0, stream>>>(Wf2, Wtf2, 2048, 1024);
  cast_bf16<<<4096, 256, 0, stream>>>(x, xb);

  gemm_bt<0, true><<<dim3(24, 32), 256, 0, stream>>>(xb, Wqkv, bq, bk, bv, QKV, NTOK, 3072, 1024);

  transpose_v<<<dim3(32, 32), 256, 0, stream>>>(QKV + 2048, Vt);
  attn_kernel<<<dim3(16, 32), 256, 0, stream>>>(QKV, QKV + 1024, Vt, ctxb);

  gemm_bt<2, false><<<dim3(8, 32), 256, 0, stream>>>(ctxb, Wto, bo, bo, bo, aout, NTOK, 1024, 1024);
  residual_ln<<<4096, 256, 0, stream>>>(x, aout, g1, b1, x1f, x1b);
  gemm_bt<1, false><<<dim3(16, 32), 256, 0, stream>>>(x1b, Wtf1, bf1, bf1, bf1, hb, NTOK, 2048, 1024);
  gemm_bt<2, false><<<dim3(8, 32), 256, 0, stream>>>(hb, Wtf2, bf2, bf2, bf2, ffo, NTOK, 1024, 2048);
  residual_ln<<<4096, 256, 0, stream>>>(x1f, ffo, g2, b2, (float*)d_out, nullptr);
}

// Round 4
// 291.707 us; speedup vs baseline: 1.4581x; 1.0163x over previous
//
#include <hip/hip_runtime.h>

#define SEQ 2048
#define NTOK 4096
#define DM 1024
#define LDQK 3072

typedef __attribute__((ext_vector_type(4))) float f32x4;
typedef __attribute__((ext_vector_type(8))) short short8;
typedef __attribute__((ext_vector_type(4))) short short4v;

__device__ __forceinline__ short f2bf(float f) {
  union { float f; unsigned u; } x; x.f = f;
  unsigned r = x.u + 0x7fffu + ((x.u >> 16) & 1u);
  return (short)(r >> 16);
}

__device__ __forceinline__ void async_load16(const void* g, void* l) {
  __builtin_amdgcn_global_load_lds(
      (const __attribute__((address_space(1))) void*)g,
      (__attribute__((address_space(3))) void*)l, 16, 0, 0);
}

// f32 [K][N] -> bf16 [N][K]
__global__ void __launch_bounds__(256) transpose_cast_w(
    const float* __restrict__ in, short* __restrict__ out, int K, int N) {
  __shared__ float t[32][33];
  const int tx = threadIdx.x, ty = threadIdx.y;
  const int n = blockIdx.x * 32 + tx;
#pragma unroll
  for (int i = 0; i < 4; ++i) {
    int k = blockIdx.y * 32 + ty + i * 8;
    t[ty + i * 8][tx] = in[(size_t)k * N + n];
  }
  __syncthreads();
  const int k2 = blockIdx.y * 32 + tx;
#pragma unroll
  for (int i = 0; i < 4; ++i) {
    int n2 = blockIdx.x * 32 + ty + i * 8;
    out[(size_t)n2 * K + k2] = f2bf(t[tx][ty + i * 8]);
  }
}

// 4x fused 1024x1024 weight transpose-casts (blockIdx.z selects tensor)
__global__ void __launch_bounds__(256) transpose_cast_w4(
    const float* __restrict__ i0, const float* __restrict__ i1,
    const float* __restrict__ i2, const float* __restrict__ i3,
    short* __restrict__ o0, short* __restrict__ o1,
    short* __restrict__ o2, short* __restrict__ o3) {
  const float* in; short* out;
  switch (blockIdx.z) {
    case 0: in = i0; out = o0; break;
    case 1: in = i1; out = o1; break;
    case 2: in = i2; out = o2; break;
    default: in = i3; out = o3; break;
  }
  __shared__ float t[32][33];
  const int tx = threadIdx.x, ty = threadIdx.y;
  const int n = blockIdx.x * 32 + tx;
#pragma unroll
  for (int i = 0; i < 4; ++i) {
    int k = blockIdx.y * 32 + ty + i * 8;
    t[ty + i * 8][tx] = in[(size_t)k * 1024 + n];
  }
  __syncthreads();
  const int k2 = blockIdx.y * 32 + tx;
#pragma unroll
  for (int i = 0; i < 4; ++i) {
    int n2 = blockIdx.x * 32 + ty + i * 8;
    out[(size_t)n2 * 1024 + k2] = f2bf(t[tx][ty + i * 8]);
  }
}

__global__ void __launch_bounds__(256) cast_bf16(
    const float* __restrict__ in, short* __restrict__ out) {
  int i = blockIdx.x * 256 + threadIdx.x;
  f32x4 v = ((const f32x4*)in)[i];
  short4v o;
#pragma unroll
  for (int j = 0; j < 4; ++j) o[j] = f2bf(v[j]);
  ((short4v*)out)[i] = o;
}

// C[M,N] = A[M,K](bf16) @ Bt[N,K](bf16)^T + bias.
// EPI: 0=bf16 out, 1=bf16 gelu, 2=f32 out. TRIPLE: bias region per 8 n-tiles.
template <int EPI, bool TRIPLE>
__global__ void __launch_bounds__(256, 2) gemm_bt(
    const short* __restrict__ A, const short* __restrict__ Bt,
    const float* __restrict__ b0, const float* __restrict__ b1,
    const float* __restrict__ b2, void* __restrict__ Cout,
    int M, int N, int K) {
  __shared__ __align__(16) short As[128 * 64];
  __shared__ __align__(16) short Bs[128 * 64];
  const int w = threadIdx.x >> 6, lane = threadIdx.x & 63;
  const int hi = lane >> 4, lo = lane & 15;
  const int bm = blockIdx.y, bn = blockIdx.x;
  const int wr = w >> 1, wc = w & 1;
  f32x4 acc[4][4] = {};
  const int nkt = K >> 6;
  for (int kt = 0; kt < nkt; ++kt) {
#pragma unroll
    for (int j = 0; j < 4; ++j) {
      int c = (j * 4 + w) * 64 + lane;  // 16B-chunk index 0..1023
      int r = c >> 3;
      int scc = (c & 7) ^ (r & 7);      // inverse-swizzled global source chunk
      async_load16(A + (size_t)(bm * 128 + r) * K + kt * 64 + scc * 8,
                   As + (j * 4 + w) * 512);
      async_load16(Bt + (size_t)(bn * 128 + r) * K + kt * 64 + scc * 8,
                   Bs + (j * 4 + w) * 512);
    }
    __syncthreads();
#pragma unroll
    for (int ks = 0; ks < 2; ++ks) {
      short8 af[4], bf[4];
#pragma unroll
      for (int m = 0; m < 4; ++m) {
        int row = wr * 64 + m * 16 + lo;
        int ch = (ks * 4 + hi) ^ (row & 7);
        af[m] = *(const short8*)(As + row * 64 + ch * 8);
      }
#pragma unroll
      for (int n = 0; n < 4; ++n) {
        int row = wc * 64 + n * 16 + lo;
        int ch = (ks * 4 + hi) ^ (row & 7);
        bf[n] = *(const short8*)(Bs + row * 64 + ch * 8);
      }
#pragma unroll
      for (int m = 0; m < 4; ++m)
#pragma unroll
        for (int n = 0; n < 4; ++n)
          acc[m][n] = __builtin_amdgcn_mfma_f32_16x16x32_bf16(af[m], bf[n], acc[m][n], 0, 0, 0);
    }
    __syncthreads();
  }
  const float* bp = b0;
  if (TRIPLE) { int r = bn >> 3; bp = (r == 0) ? b0 : ((r == 1) ? b1 : b2); }
  const int colb = bn * 128 + wc * 64 + lo;
#pragma unroll
  for (int m = 0; m < 4; ++m) {
    int row0 = bm * 128 + wr * 64 + m * 16 + hi * 4;
#pragma unroll
    for (int n = 0; n < 4; ++n) {
      int col = colb + n * 16;
      float bs = bp[TRIPLE ? (col & 1023) : col];
#pragma unroll
      for (int j = 0; j < 4; ++j) {
        float v = acc[m][n][j] + bs;
        if (EPI == 1) v = 0.5f * v * (1.f + erff(v * 0.70710678f));
        size_t idx = (size_t)(row0 + j) * N + col;
        if (EPI == 2) ((float*)Cout)[idx] = v;
        else ((short*)Cout)[idx] = f2bf(v);
      }
    }
  }
}

// V section of QKV [tok][LDQK] -> Vt [B*H][64][SEQ]
__global__ void __launch_bounds__(256) transpose_v(
    const short* __restrict__ Vb, short* __restrict__ Vt) {
  __shared__ short t[64][65];
  const int bh = blockIdx.y, s0 = blockIdx.x * 64;
  const int b = bh >> 4, h = bh & 15;
  const int tid = threadIdx.x;
#pragma unroll
  for (int i = 0; i < 16; ++i) {
    int e = i * 256 + tid;
    int r = e >> 6, c = e & 63;
    t[c][r] = Vb[(size_t)(b * SEQ + s0 + r) * LDQK + h * 64 + c];
  }
  __syncthreads();
#pragma unroll
  for (int i = 0; i < 16; ++i) {
    int e = i * 256 + tid;
    int d = e >> 6, sc = e & 63;
    Vt[(size_t)bh * 64 * SEQ + (size_t)d * SEQ + s0 + sc] = t[d][sc];
  }
}

// Flash attention. grid 512 blocks, 4 waves x 32 q-rows, KVBLK=128.
// Swapped QK^T (P lane-local per q-row=lo), P staged via wave-private
// XOR-swizzled LDS (no barriers), defer-rescale THR=8, XCD-chunked swizzle.
__global__ void __launch_bounds__(256, 2) attn_kernel(
    const short* __restrict__ Qb, const short* __restrict__ Kb,
    const short* __restrict__ Vt, short* __restrict__ ctx) {
  const int w = threadIdx.x >> 6, lane = threadIdx.x & 63;
  const int hi = lane >> 4, lo = lane & 15;
  // hw-linear id L -> logical W, contiguous 64-block chunk per XCD (nwg=512)
  const int L = blockIdx.y * 16 + blockIdx.x;
  const int W = (L & 7) * 64 + (L >> 3);
  const int qt = W & 15, bh = W >> 4;
  const int b = bh >> 4, h = bh & 15;
  const int qbase = qt * 128 + w * 32;
  const float C = 0.18033688f;  // 0.125 * log2(e)

  __shared__ __align__(16) short P[4][2][16][128];  // [wave][u][qrow][k] 32KB

  const short* qp = Qb + (size_t)(b * SEQ + qbase + lo) * LDQK + h * 64;
  short8 bq[2][2];
#pragma unroll
  for (int u = 0; u < 2; ++u)
#pragma unroll
    for (int c = 0; c < 2; ++c)
      bq[u][c] = *(const short8*)(qp + (size_t)u * 16 * LDQK + c * 32 + hi * 8);

  const short* kb = Kb + (size_t)(b * SEQ) * LDQK + h * 64;
  const short* vb = Vt + (size_t)bh * 64 * SEQ;

  f32x4 o[2][4] = {};
  float m[2] = {-1e30f, -1e30f}, l[2] = {0.f, 0.f};

  for (int kt = 0; kt < SEQ / 128; ++kt) {
    f32x4 s[2][8] = {};
    const short* kbase = kb + (size_t)(kt * 128 + lo) * LDQK;
#pragma unroll
    for (int g = 0; g < 8; ++g) {
      short8 ka0 = *(const short8*)(kbase + (size_t)g * 16 * LDQK + hi * 8);
      short8 ka1 = *(const short8*)(kbase + (size_t)g * 16 * LDQK + 32 + hi * 8);
      s[0][g] = __builtin_amdgcn_mfma_f32_16x16x32_bf16(ka0, bq[0][0], s[0][g], 0, 0, 0);
      s[1][g] = __builtin_amdgcn_mfma_f32_16x16x32_bf16(ka0, bq[1][0], s[1][g], 0, 0, 0);
      s[0][g] = __builtin_amdgcn_mfma_f32_16x16x32_bf16(ka1, bq[0][1], s[0][g], 0, 0, 0);
      s[1][g] = __builtin_amdgcn_mfma_f32_16x16x32_bf16(ka1, bq[1][1], s[1][g], 0, 0, 0);
    }
    short8 vv[4][4];
#pragma unroll
    for (int ks = 0; ks < 4; ++ks)
#pragma unroll
      for (int a = 0; a < 4; ++a)
        vv[ks][a] = *(const short8*)(vb + (size_t)(a * 16 + lo) * SEQ + kt * 128 + ks * 32 + hi * 8);
#pragma unroll
    for (int u = 0; u < 2; ++u) {
      float mt = -1e30f;
#pragma unroll
      for (int g = 0; g < 8; ++g)
#pragma unroll
        for (int j = 0; j < 4; ++j) mt = fmaxf(mt, s[u][g][j]);
      mt = fmaxf(mt, __shfl_xor(mt, 16));
      mt = fmaxf(mt, __shfl_xor(mt, 32));
      if (!__all(mt <= m[u] + 8.f)) {   // defer-rescale (T13, THR=8)
        float mnew = fmaxf(m[u], mt);
        float alpha = exp2f((m[u] - mnew) * C);
        l[u] *= alpha;
        m[u] = mnew;
#pragma unroll
        for (int j = 0; j < 4; ++j) {
          float aj = __shfl(alpha, hi * 4 + j);
#pragma unroll
          for (int a = 0; a < 4; ++a) o[u][a][j] *= aj;
        }
      }
      float rs = 0.f;
      float mC = m[u] * C;
      short* pbase = &P[w][u][0][0];
#pragma unroll
      for (int g = 0; g < 8; ++g) {
        short4v t;
#pragma unroll
        for (int j = 0; j < 4; ++j) {
          float p = exp2f(s[u][g][j] * C - mC);
          rs += p;
          t[j] = f2bf(p);
        }
        // logical chunk 2g+(hi>>1), physical ^= (row&7); row = lo
        int pc = (2 * g + (hi >> 1)) ^ (lo & 7);
        *(short4v*)(pbase + lo * 128 + pc * 8 + (hi & 1) * 4) = t;
      }
      rs += __shfl_xor(rs, 16);
      rs += __shfl_xor(rs, 32);
      l[u] += rs;
#pragma unroll
      for (int ks = 0; ks < 4; ++ks) {
        int pc = (ks * 4 + hi) ^ (lo & 7);
        short8 pa = *(const short8*)(pbase + lo * 128 + pc * 8);
#pragma unroll
        for (int a = 0; a < 4; ++a)
          o[u][a] = __builtin_amdgcn_mfma_f32_16x16x32_bf16(pa, vv[ks][a], o[u][a], 0, 0, 0);
      }
    }
  }
#pragma unroll
  for (int u = 0; u < 2; ++u)
#pragma unroll
    for (int j = 0; j < 4; ++j) {
      float lj = __shfl(l[u], hi * 4 + j);
      float inv = 1.f / lj;
      int row = qbase + u * 16 + hi * 4 + j;
#pragma unroll
      for (int a = 0; a < 4; ++a)
        ctx[(size_t)(b * SEQ + row) * DM + h * 64 + a * 16 + lo] = f2bf(o[u][a][j] * inv);
    }
}

// out = LN(x + y)*g + beta ; optional bf16 copy
__global__ void __launch_bounds__(256) residual_ln(
    const float* __restrict__ xr, const float* __restrict__ yr,
    const float* __restrict__ g, const float* __restrict__ beta,
    float* __restrict__ outf, short* __restrict__ outb) {
  const int row = blockIdx.x;
  const int t = threadIdx.x;
  const size_t base = (size_t)row * DM;
  f32x4 xv = ((const f32x4*)(xr + base))[t];
  f32x4 yv = ((const f32x4*)(yr + base))[t];
  f32x4 v = xv + yv;
  float s = v[0] + v[1] + v[2] + v[3];
  float s2 = v[0] * v[0] + v[1] * v[1] + v[2] * v[2] + v[3] * v[3];
#pragma unroll
  for (int off = 1; off < 64; off <<= 1) {
    s += __shfl_xor(s, off);
    s2 += __shfl_xor(s2, off);
  }
  __shared__ float rs[4], rs2[4];
  if ((t & 63) == 0) { rs[t >> 6] = s; rs2[t >> 6] = s2; }
  __syncthreads();
  s = rs[0] + rs[1] + rs[2] + rs[3];
  s2 = rs2[0] + rs2[1] + rs2[2] + rs2[3];
  float mu = s * (1.f / DM);
  float var = s2 * (1.f / DM) - mu * mu;
  float rstd = rsqrtf(var + 1e-5f);
  f32x4 gv = ((const f32x4*)g)[t];
  f32x4 bv = ((const f32x4*)beta)[t];
  f32x4 ov;
#pragma unroll
  for (int j = 0; j < 4; ++j) ov[j] = (v[j] - mu) * rstd * gv[j] + bv[j];
  ((f32x4*)(outf + base))[t] = ov;
  if (outb) {
    short4v sb;
#pragma unroll
    for (int j = 0; j < 4; ++j) sb[j] = f2bf(ov[j]);
    ((short4v*)(outb + base))[t] = sb;
  }
}

extern "C" void kernel_launch(void* const* d_in, const int* in_sizes, int n_in,
                              void* d_out, int out_size, void* d_ws, size_t ws_size,
                              hipStream_t stream) {
  (void)in_sizes; (void)n_in; (void)out_size; (void)ws_size;
  const float* x   = (const float*)d_in[0];
  const float* Wq  = (const float*)d_in[1];
  const float* bq  = (const float*)d_in[2];
  const float* Wk  = (const float*)d_in[3];
  const float* bk  = (const float*)d_in[4];
  const float* Wv  = (const float*)d_in[5];
  const float* bv  = (const float*)d_in[6];
  const float* Wo  = (const float*)d_in[7];
  const float* bo  = (const float*)d_in[8];
  const float* g1  = (const float*)d_in[9];
  const float* b1  = (const float*)d_in[10];
  const float* Wf1 = (const float*)d_in[11];
  const float* bf1 = (const float*)d_in[12];
  const float* Wf2 = (const float*)d_in[13];
  const float* bf2 = (const float*)d_in[14];
  const float* g2  = (const float*)d_in[15];
  const float* b2  = (const float*)d_in[16];

  char* ws = (char*)d_ws;
  const size_t MB = 1u << 20;
  short* Wqkv = (short*)(ws + 0 * MB);    // [3072][1024] bf16, 6 MB
  short* Wto  = (short*)(ws + 6 * MB);    // 2 MB
  short* Wtf1 = (short*)(ws + 8 * MB);    // 4 MB
  short* Wtf2 = (short*)(ws + 12 * MB);   // 4 MB
  short* xb   = (short*)(ws + 16 * MB);   // 8 MB
  short* QKV  = (short*)(ws + 24 * MB);   // [4096][3072] bf16, 24 MB
  short* Vt   = (short*)(ws + 48 * MB);   // 8 MB
  short* ctxb = (short*)(ws + 56 * MB);   // 8 MB
  float* aout = (float*)(ws + 64 * MB);   // 16 MB
  float* x1f  = (float*)(ws + 80 * MB);   // 16 MB
  short* x1b  = xb;                        // xb dead after QKV gemm
  short* hb   = QKV;                       // QKV dead after attention
  float* ffo  = (float*)(ws + 48 * MB);   // Vt+ctxb dead after O-proj

  dim3 b32(32, 8, 1);
  transpose_cast_w4<<<dim3(32, 32, 4), b32, 0, stream>>>(
      Wq, Wk, Wv, Wo, Wqkv, Wqkv + 1024 * 1024, Wqkv + 2048 * 1024, Wto);
  transpose_cast_w<<<dim3(64, 32), b32, 0, stream>>>(Wf1, Wtf1, 1024, 2048);
  transpose_cast_w<<<dim3(32, 64), b32, 0, stream>>>(Wf2, Wtf2, 2048, 1024);
  cast_bf16<<<4096, 256, 0, stream>>>(x, xb);

  gemm_bt<0, true><<<dim3(24, 32), 256, 0, stream>>>(xb, Wqkv, bq, bk, bv, QKV, NTOK, 3072, 1024);

  transpose_v<<<dim3(32, 32), 256, 0, stream>>>(QKV + 2048, Vt);
  attn_kernel<<<dim3(16, 32), 256, 0, stream>>>(QKV, QKV + 1024, Vt, ctxb);

  gemm_bt<2, false><<<dim3(8, 32), 256, 0, stream>>>(ctxb, Wto, bo, bo, bo, aout, NTOK, 1024, 1024);
  residual_ln<<<4096, 256, 0, stream>>>(x, aout, g1, b1, x1f, x1b);
  gemm_bt<1, false><<<dim3(16, 32), 256, 0, stream>>>(x1b, Wtf1, bf1, bf1, bf1, hb, NTOK, 2048, 1024);
  gemm_bt<2, false><<<dim3(8, 32), 256, 0, stream>>>(hb, Wtf2, bf2, bf2, bf2, ffo, NTOK, 1024, 2048);
  residual_ln<<<4096, 256, 0, stream>>>(x1f, ffo, g2, b2, (float*)d_out, nullptr);
}